// Round 1
// baseline (1398.771 us; speedup 1.0000x reference)
//
#include <hip/hip_runtime.h>

typedef unsigned short u16;
typedef __attribute__((ext_vector_type(8))) short bf16x8;
typedef __attribute__((ext_vector_type(4))) float f32x4;

__device__ __forceinline__ float bf2f(u16 u) {
  union { unsigned int i; float f; } v; v.i = ((unsigned int)u) << 16; return v.f;
}
__device__ __forceinline__ u16 f2bf(float f) {
  union { float f; unsigned int i; } v; v.f = f;
  unsigned int r = (v.i + 0x7FFFu + ((v.i >> 16) & 1u)) >> 16;
  return (u16)r;
}
__device__ __forceinline__ float sigmoidf_(float x) { return 1.f / (1.f + __expf(-x)); }
__device__ __forceinline__ float tanhf_(float x) {
  x = fminf(fmaxf(x, -10.f), 10.f);
  float e2 = __expf(2.f * x);
  return (e2 - 1.f) / (e2 + 1.f);
}

// ---------------- workspace layout (bytes) ----------------
static const size_t OFF_GX    = 0;              // bf16 [8192][3072]
static const size_t OFF_HBUF  = 50331648;       // bf16 [2][257][32][512]
static const size_t OFF_ASRC  = 67174400;       // bf16 [8192][512]
static const size_t OFF_EW1   = 75563008;       // bf16 [8192][1024]
static const size_t OFF_B1    = 92340224;       // f32  [8192][512]
static const size_t OFF_WIHC  = 109117440;      // bf16 [3072][512]
static const size_t OFF_WWB   = 112263168;      // bf16 [512][1024]
static const size_t OFF_WO2B  = 113311744;      // bf16 [512][1024]
static const size_t OFF_WKB   = 114360320;      // bf16 [512][512]
static const size_t OFF_KWE   = 114884608;      // bf16 [512][512]
static const size_t OFF_B3    = 115408896;      // f32  [512][512]   row = b*16+t
static const size_t OFF_TP    = 116457472;      // f32  [32][512]
static const size_t OFF_TPO   = 116523008;      // f32  [32][512]
static const size_t OFF_SSUM  = 116588544;      // f32  [8192]
static const size_t OFF_BIASC = 116621312;      // f32  [3072]
static const size_t OFF_CNT   = 116633600;      // int  [2][257]

// ---------------- small prep kernels ----------------
__global__ __launch_bounds__(256) void cvtk(const float* __restrict__ s,
                                            u16* __restrict__ d, int n) {
  int i = (blockIdx.x * 256 + threadIdx.x) * 4;
  if (i < n) {
    float4 v = *(const float4*)(s + i);
    ushort4 o; o.x = f2bf(v.x); o.y = f2bf(v.y); o.z = f2bf(v.z); o.w = f2bf(v.w);
    *(ushort4*)(d + i) = o;
  }
}

// Wo2B[n][k] = Wo[n][512+k], n<512, k<1024
__global__ __launch_bounds__(256) void cvt_wo2(const float* __restrict__ Wo,
                                               u16* __restrict__ d) {
  int i = (blockIdx.x * 256 + threadIdx.x) * 4;  // over 512*1024
  int nrow = i >> 10, c = i & 1023;
  float4 v = *(const float4*)(Wo + (size_t)nrow * 1536 + 512 + c);
  ushort4 o; o.x = f2bf(v.x); o.y = f2bf(v.y); o.z = f2bf(v.z); o.w = f2bf(v.w);
  *(ushort4*)(d + i) = o;
}

// mode 0: row r uses ids[r]; mode 1 (kwemb, row=b*16+t): ids[(r&15)*32 + (r>>4)]
__global__ __launch_bounds__(256) void gather_rows(const int* __restrict__ ids,
                                                   const float* __restrict__ tab,
                                                   u16* __restrict__ dst, int mode) {
  int i = (blockIdx.x * 256 + threadIdx.x) * 8;
  int r = i >> 9, c = i & 511;
  int id = (mode == 0) ? ids[r] : ids[((r & 15) << 5) + (r >> 4)];
  const float* s = tab + (size_t)id * 512 + c;
  alignas(16) u16 o[8];
#pragma unroll
  for (int j = 0; j < 8; ++j) o[j] = f2bf(s[j]);
  *(uint4*)(dst + i) = *(const uint4*)o;
}

// tp[b][n] = bt[n] + sum_h theme_tab[theme[b]][h] * Wt[n][h]
__global__ __launch_bounds__(256) void proj_tp(const int* __restrict__ theme,
                                               const float* __restrict__ tab,
                                               const float* __restrict__ W,
                                               const float* __restrict__ bias,
                                               float* __restrict__ outp) {
  int o = blockIdx.x * 256 + threadIdx.x;  // 16384
  int b = o >> 9, n = o & 511;
  const float* emb = tab + (size_t)theme[b] * 512;
  const float* wr = W + (size_t)n * 512;
  float acc = 0.f;
  for (int h = 0; h < 512; h += 4) {
    float4 e = *(const float4*)(emb + h);
    float4 w = *(const float4*)(wr + h);
    acc += e.x * w.x + e.y * w.y + e.z * w.z + e.w * w.w;
  }
  outp[o] = acc + bias[n];
}

// tpo[b][n] = sum_h tp[b][h] * Wo[n][h]   (Wo1 = cols 0..511 of Wo rows)
__global__ __launch_bounds__(256) void proj_tpo(const float* __restrict__ tp,
                                                const float* __restrict__ Wo,
                                                float* __restrict__ outp) {
  int o = blockIdx.x * 256 + threadIdx.x;
  int b = o >> 9, n = o & 511;
  const float* emb = tp + (size_t)b * 512;
  const float* wr = Wo + (size_t)n * 1536;
  float acc = 0.f;
  for (int h = 0; h < 512; h += 4) {
    float4 e = *(const float4*)(emb + h);
    float4 w = *(const float4*)(wr + h);
    acc += e.x * w.x + e.y * w.y + e.z * w.z + e.w * w.w;
  }
  outp[o] = acc;
}

// ---------------- shared GEMM: C[M][N] = A(MxK,bf16) * B(NxK,bf16)^T ----------------
// EPI 0: out bf16 = acc + bias ; EPI 1: out f32 = acc + bias
// EPI 2: out f32 = acc + bias + ssum[row]*tpo[(row&31)*512+col]
template <int EPI>
__global__ __launch_bounds__(256) void gemm_bt(const u16* __restrict__ A,
                                               const u16* __restrict__ B,
                                               const float* __restrict__ bias,
                                               float* __restrict__ Cf,
                                               u16* __restrict__ Cb, int M, int N,
                                               int K, const float* __restrict__ ssum,
                                               const float* __restrict__ tpo) {
  __shared__ u16 As[128][72];
  __shared__ u16 Bs[128][72];
  const int tid = threadIdx.x;
  const int mtiles = M >> 7;
  const int mt = blockIdx.x % mtiles, nt = blockIdx.x / mtiles;
  const int wave = tid >> 6, lane = tid & 63;
  const int wr = wave >> 1, wc = wave & 1;
  const int l16 = lane & 15, l4 = lane >> 4;
  f32x4 acc[4][4] = {};
  const int nkt = K >> 6;
  for (int kt = 0; kt < nkt; ++kt) {
    __syncthreads();
#pragma unroll
    for (int i = 0; i < 4; ++i) {
      int c = i * 256 + tid;
      int row = c >> 3, c8 = c & 7;
      uint4 va = *(const uint4*)(A + (size_t)(mt * 128 + row) * K + kt * 64 + c8 * 8);
      *(uint4*)&As[row][c8 * 8] = va;
      uint4 vb = *(const uint4*)(B + (size_t)(nt * 128 + row) * K + kt * 64 + c8 * 8);
      *(uint4*)&Bs[row][c8 * 8] = vb;
    }
    __syncthreads();
#pragma unroll
    for (int kk = 0; kk < 2; ++kk) {
      bf16x8 af[4], bfr[4];
#pragma unroll
      for (int m = 0; m < 4; ++m)
        af[m] = *(const bf16x8*)&As[wr * 64 + m * 16 + l16][kk * 32 + l4 * 8];
#pragma unroll
      for (int n = 0; n < 4; ++n)
        bfr[n] = *(const bf16x8*)&Bs[wc * 64 + n * 16 + l16][kk * 32 + l4 * 8];
#pragma unroll
      for (int m = 0; m < 4; ++m)
#pragma unroll
        for (int n = 0; n < 4; ++n)
          acc[m][n] = __builtin_amdgcn_mfma_f32_16x16x32_bf16(af[m], bfr[n],
                                                              acc[m][n], 0, 0, 0);
    }
  }
#pragma unroll
  for (int m = 0; m < 4; ++m) {
    int rg = mt * 128 + wr * 64 + m * 16 + l4 * 4;
#pragma unroll
    for (int n = 0; n < 4; ++n) {
      int cg = nt * 128 + wc * 64 + n * 16 + l16;
      float bb = bias[cg];
#pragma unroll
      for (int i = 0; i < 4; ++i) {
        int r = rg + i;
        float v = acc[m][n][i] + bb;
        if (EPI == 2) v += ssum[r] * tpo[(r & 31) * 512 + cg];
        if (EPI == 0) Cb[(size_t)r * N + cg] = f2bf(v);
        else Cf[(size_t)r * N + cg] = v;
      }
    }
  }
}

// ---------------- GRU scan: 32 persistent WGs (2 dirs x 16 slices) ----------------
__global__ __launch_bounds__(256) void gru_scan(const u16* __restrict__ gx,  // [8192][3072]
                                                const float* __restrict__ Whh_f,
                                                const float* __restrict__ Whh_b,
                                                const float* __restrict__ bhh_f,
                                                const float* __restrict__ bhh_b,
                                                u16* __restrict__ hbuf,  // [2][257][32][512]
                                                int* __restrict__ cnt)   // [2][257]
{
  __shared__ u16 Wl[96][520];     // Whh slice, bf16, padded
  __shared__ u16 hl[32 * 512];    // full h, bf16, XOR-swizzled rows
  __shared__ float gh[32][100];   // mfma result
  __shared__ float hF[32][32];    // own slice master f32 state
  __shared__ float bhs[96];
  const int tid = threadIdx.x;
  const int bid = blockIdx.x;
  const int r8 = bid & 7;
  const int d = r8 >> 2;
  const int slice = (bid >> 3) * 4 + (r8 & 3);
  const float* Whh = d ? Whh_b : Whh_f;
  const float* bhh = d ? bhh_b : bhh_f;

  for (int e = tid * 4; e < 96 * 512; e += 1024) {
    int lr = e >> 9, c = e & 511;
    int grow = (lr >> 5) * 512 + slice * 32 + (lr & 31);
    float4 v = *(const float4*)(Whh + (size_t)grow * 512 + c);
    ushort4 o; o.x = f2bf(v.x); o.y = f2bf(v.y); o.z = f2bf(v.z); o.w = f2bf(v.w);
    *(ushort4*)&Wl[lr][c] = o;
  }
  if (tid < 96) {
    int grow = (tid >> 5) * 512 + slice * 32 + (tid & 31);
    bhs[tid] = bhh[grow];
  }
  for (int e = tid; e < 32 * 32; e += 256) hF[e >> 5][e & 31] = 0.f;

  const int wave = tid >> 6, lane = tid & 63;
  const int l16 = lane & 15, l4 = lane >> 4;
  const int mt = wave & 1, nt3 = (wave >> 1) * 3;
  const int arow = mt * 16 + l16;
  const int asw = (arow & 7) << 4;
  int* cntd = cnt + d * 257;

  __syncthreads();

  for (int t = 0; t < 256; ++t) {
    // issue gx loads early (independent of h) to hide latency behind the poll
    int trow = (d == 0) ? t : 255 - t;
    const u16* gxr = gx + (size_t)trow * 32 * 3072 + d * 1536 + slice * 32;
    float xr[4], xz[4], xn[4];
#pragma unroll
    for (int it = 0; it < 4; ++it) {
      int item = it * 256 + tid;
      int b = item >> 5, j = item & 31;
      const u16* gxb = gxr + (size_t)b * 3072;
      xr[it] = bf2f(gxb[j]);
      xz[it] = bf2f(gxb[512 + j]);
      xn[it] = bf2f(gxb[1024 + j]);
    }
    if (t > 0) {
      if (tid == 0) {
        while (__hip_atomic_load(cntd + t, __ATOMIC_ACQUIRE,
                                 __HIP_MEMORY_SCOPE_AGENT) < 16)
          __builtin_amdgcn_s_sleep(1);
      }
      __syncthreads();
    }
    // stage full h (32x512 bf16) into LDS, swizzled
    const u16* hsrc = hbuf + ((size_t)(d * 257 + t) * 32) * 512;
#pragma unroll
    for (int i = 0; i < 8; ++i) {
      int idx = i * 256 + tid;
      int row = idx >> 6, cb = idx & 63;
      uint4 v = *(const uint4*)(hsrc + row * 512 + cb * 8);
      *(uint4*)((char*)hl + row * 1024 + ((cb * 16) ^ ((row & 7) << 4))) = v;
    }
    __syncthreads();
    // gh(32x96) = h(32x512) @ Whh_slice^T
    f32x4 a0 = {}, a1 = {}, a2 = {};
    const char* hlb = (const char*)hl;
#pragma unroll
    for (int k = 0; k < 16; ++k) {
      int abyte = arow * 1024 + (((k * 32 + l4 * 8) * 2) ^ asw);
      bf16x8 av = *(const bf16x8*)(hlb + abyte);
      bf16x8 b0 = *(const bf16x8*)&Wl[(nt3 + 0) * 16 + l16][k * 32 + l4 * 8];
      bf16x8 b1v = *(const bf16x8*)&Wl[(nt3 + 1) * 16 + l16][k * 32 + l4 * 8];
      bf16x8 b2 = *(const bf16x8*)&Wl[(nt3 + 2) * 16 + l16][k * 32 + l4 * 8];
      a0 = __builtin_amdgcn_mfma_f32_16x16x32_bf16(av, b0, a0, 0, 0, 0);
      a1 = __builtin_amdgcn_mfma_f32_16x16x32_bf16(av, b1v, a1, 0, 0, 0);
      a2 = __builtin_amdgcn_mfma_f32_16x16x32_bf16(av, b2, a2, 0, 0, 0);
    }
    {
      int crow = mt * 16 + l4 * 4;
#pragma unroll
      for (int i = 0; i < 4; ++i) {
        gh[crow + i][(nt3 + 0) * 16 + l16] = a0[i];
        gh[crow + i][(nt3 + 1) * 16 + l16] = a1[i];
        gh[crow + i][(nt3 + 2) * 16 + l16] = a2[i];
      }
    }
    __syncthreads();
    // gates + state update + publish own slice
    u16* hdst = hbuf + ((size_t)(d * 257 + t + 1) * 32) * 512 + slice * 32;
#pragma unroll
    for (int it = 0; it < 4; ++it) {
      int item = it * 256 + tid;
      int b = item >> 5, j = item & 31;
      float hr = gh[b][j] + bhs[j];
      float hz = gh[b][32 + j] + bhs[32 + j];
      float hn = gh[b][64 + j] + bhs[64 + j];
      float rr = sigmoidf_(xr[it] + hr);
      float zz = sigmoidf_(xz[it] + hz);
      float nn = tanhf_(xn[it] + rr * hn);
      float hp = hF[b][j];
      float hnew = (1.f - zz) * nn + zz * hp;
      hF[b][j] = hnew;
      hdst[(size_t)b * 512 + j] = f2bf(hnew);
    }
    __syncthreads();
    if (tid == 0)
      __hip_atomic_fetch_add(cntd + t + 1, 1, __ATOMIC_RELEASE,
                             __HIP_MEMORY_SCOPE_AGENT);
  }
}

// enc_w1[r][0:512] = ys_f[s][b] = hbuf[0][s+1][b]; [512:1024] = ys_b[s][b] = hbuf[1][256-s][b]
__global__ __launch_bounds__(256) void build_encw1(const u16* __restrict__ hbuf,
                                                   u16* __restrict__ ew) {
  int idx = (blockIdx.x * 256 + threadIdx.x) * 8;
  int r = idx >> 10, c = idx & 1023;
  int s = r >> 5, b = r & 31;
  size_t src;
  if (c < 512) src = ((size_t)(s + 1) * 32 + b) * 512 + c;
  else src = ((size_t)(257 + 256 - s) * 32 + b) * 512 + (c - 512);
  *(uint4*)(ew + idx) = *(const uint4*)(hbuf + src);
}

// ssum[r] = sum_t sum_h wv[h]*tanh(b1[r][h] + tp[b][h] + b3[b*16+t][h]) + 16*bv
__global__ __launch_bounds__(256) void scores_k(const float* __restrict__ b1,
                                                const float* __restrict__ tp,
                                                const float* __restrict__ b3,
                                                const float* __restrict__ wv,
                                                const float* __restrict__ bv,
                                                float* __restrict__ ssum) {
  __shared__ float pre[512];
  __shared__ float wvs[512];
  __shared__ float red[4];
  int r = blockIdx.x;
  int tid = threadIdx.x;
  int b = r & 31;
  for (int h = tid; h < 512; h += 256) {
    pre[h] = b1[(size_t)r * 512 + h] + tp[b * 512 + h];
    wvs[h] = wv[h];
  }
  __syncthreads();
  float acc = 0.f;
  for (int t = 0; t < 16; ++t) {
    const float* b3r = b3 + ((size_t)b * 16 + t) * 512;
    for (int h = tid; h < 512; h += 256) acc += wvs[h] * tanhf_(pre[h] + b3r[h]);
  }
  for (int o = 32; o > 0; o >>= 1) acc += __shfl_down(acc, o);
  if ((tid & 63) == 0) red[tid >> 6] = acc;
  __syncthreads();
  if (tid == 0) ssum[r] = red[0] + red[1] + red[2] + red[3] + 16.f * bv[0];
}

// enc_hidden_out[b][n] = sum_k [hT_f|hT_b][b][k] * Who[n][k]
__global__ __launch_bounds__(256) void hidden_k(const u16* __restrict__ hbuf,
                                                const float* __restrict__ Who,
                                                float* __restrict__ outp) {
  int o = blockIdx.x * 256 + threadIdx.x;  // 16384
  int b = o >> 9, n = o & 511;
  const u16* hf = hbuf + ((size_t)256 * 32 + b) * 512;
  const u16* hb = hbuf + ((size_t)(257 + 256) * 32 + b) * 512;
  const float* w = Who + (size_t)n * 1024;
  float acc = 0.f;
  for (int k = 0; k < 512; ++k) acc += bf2f(hf[k]) * w[k];
  for (int k = 0; k < 512; ++k) acc += bf2f(hb[k]) * w[512 + k];
  outp[o] = acc;
}

extern "C" void kernel_launch(void* const* d_in, const int* in_sizes, int n_in,
                              void* d_out, int out_size, void* d_ws, size_t ws_size,
                              hipStream_t stream) {
  (void)in_sizes; (void)n_in; (void)out_size; (void)ws_size;
  const int* theme = (const int*)d_in[0];
  const int* keyword = (const int*)d_in[1];
  const int* src = (const int*)d_in[2];
  const float* theme_tab = (const float*)d_in[3];
  const float* keyword_tab = (const float*)d_in[4];
  const float* src_tab = (const float*)d_in[5];
  const float* Wih_f = (const float*)d_in[6];
  const float* Whh_f = (const float*)d_in[7];
  const float* bih_f = (const float*)d_in[8];
  const float* bhh_f = (const float*)d_in[9];
  const float* Wih_b = (const float*)d_in[10];
  const float* Whh_b = (const float*)d_in[11];
  const float* bih_b = (const float*)d_in[12];
  const float* bhh_b = (const float*)d_in[13];
  const float* Ww = (const float*)d_in[14];
  const float* bw = (const float*)d_in[15];
  const float* Wt = (const float*)d_in[16];
  const float* bt = (const float*)d_in[17];
  const float* Wk = (const float*)d_in[18];
  const float* bk = (const float*)d_in[19];
  const float* wv = (const float*)d_in[20];
  const float* bv = (const float*)d_in[21];
  const float* Wo = (const float*)d_in[22];
  const float* bo = (const float*)d_in[23];
  const float* Who = (const float*)d_in[24];
  float* out = (float*)d_out;
  char* ws = (char*)d_ws;

  u16* gx_cat = (u16*)(ws + OFF_GX);
  u16* hbuf = (u16*)(ws + OFF_HBUF);
  u16* asrc = (u16*)(ws + OFF_ASRC);
  u16* ew1 = (u16*)(ws + OFF_EW1);
  float* b1buf = (float*)(ws + OFF_B1);
  u16* wihc = (u16*)(ws + OFF_WIHC);
  u16* wwb = (u16*)(ws + OFF_WWB);
  u16* wo2b = (u16*)(ws + OFF_WO2B);
  u16* wkb = (u16*)(ws + OFF_WKB);
  u16* kwe = (u16*)(ws + OFF_KWE);
  float* b3buf = (float*)(ws + OFF_B3);
  float* tp = (float*)(ws + OFF_TP);
  float* tpo = (float*)(ws + OFF_TPO);
  float* ssum = (float*)(ws + OFF_SSUM);
  float* biasc = (float*)(ws + OFF_BIASC);
  int* cnt = (int*)(ws + OFF_CNT);

  // init: sync counters + h0 = 0
  hipMemsetAsync(cnt, 0, 2 * 257 * 4, stream);
  hipMemsetAsync(hbuf, 0, 32 * 512 * 2, stream);
  hipMemsetAsync(hbuf + (size_t)257 * 32 * 512, 0, 32 * 512 * 2, stream);
  // bias_cat = [bih_f, bih_b]
  hipMemcpyAsync(biasc, bih_f, 1536 * 4, hipMemcpyDeviceToDevice, stream);
  hipMemcpyAsync(biasc + 1536, bih_b, 1536 * 4, hipMemcpyDeviceToDevice, stream);

  // weight conversions
  cvtk<<<768, 256, 0, stream>>>(Wih_f, wihc, 1536 * 512);
  cvtk<<<768, 256, 0, stream>>>(Wih_b, wihc + 1536 * 512, 1536 * 512);
  cvtk<<<512, 256, 0, stream>>>(Ww, wwb, 512 * 1024);
  cvtk<<<256, 256, 0, stream>>>(Wk, wkb, 512 * 512);
  cvt_wo2<<<512, 256, 0, stream>>>(Wo, wo2b);
  // gathers
  gather_rows<<<2048, 256, 0, stream>>>(src, src_tab, asrc, 0);
  gather_rows<<<128, 256, 0, stream>>>(keyword, keyword_tab, kwe, 1);
  // small projections
  proj_tp<<<64, 256, 0, stream>>>(theme, theme_tab, Wt, bt, tp);
  proj_tpo<<<64, 256, 0, stream>>>(tp, Wo, tpo);
  // b3 = kwemb @ Wk^T + bk   (M=512,N=512,K=512)
  gemm_bt<1><<<16, 256, 0, stream>>>(kwe, wkb, bk, b3buf, nullptr, 512, 512, 512,
                                     nullptr, nullptr);
  // gx = src_emb @ [Wih_f;Wih_b]^T + bih  (M=8192,N=3072,K=512) -> bf16
  gemm_bt<0><<<1536, 256, 0, stream>>>(asrc, wihc, biasc, nullptr, gx_cat, 8192,
                                       3072, 512, nullptr, nullptr);
  // sequential bidirectional GRU
  gru_scan<<<32, 256, 0, stream>>>(gx_cat, Whh_f, Whh_b, bhh_f, bhh_b, hbuf, cnt);
  // enc_w_1 materialization
  build_encw1<<<4096, 256, 0, stream>>>(hbuf, ew1);
  // b1 = enc_w_1 @ Ww^T + bw  (M=8192,N=512,K=1024) -> f32
  gemm_bt<1><<<256, 256, 0, stream>>>(ew1, wwb, bw, b1buf, nullptr, 8192, 512, 1024,
                                      nullptr, nullptr);
  // attention scalar per (s,b)
  scores_k<<<8192, 256, 0, stream>>>(b1buf, tp, b3buf, wv, bv, ssum);
  // enc_out = enc_w1 @ Wo2^T + bo + ssum*tpo  -> d_out (f32)
  gemm_bt<2><<<256, 256, 0, stream>>>(ew1, wo2b, bo, out, nullptr, 8192, 512, 1024,
                                      ssum, tpo);
  // enc_hidden_out
  hidden_k<<<64, 256, 0, stream>>>(hbuf, Who, out + 4194304);
}